// Round 10
// baseline (435.947 us; speedup 1.0000x reference)
//
#include <hip/hip_runtime.h>

typedef short s16x8 __attribute__((ext_vector_type(8)));
typedef float f32x4 __attribute__((ext_vector_type(4)));
typedef float f32x2 __attribute__((ext_vector_type(2)));

#define TID threadIdx.x

__device__ __forceinline__ float lrelu_f(float x) { return fmaxf(x, 0.33f * x); }

// lrelu(pv+q.x), lrelu(pv+q.y) -> packed bf16x2 using HW v_cvt_pk_bf16_f32
__device__ __forceinline__ unsigned lrelu_pack(float pv, f32x2 q) {
    f32x2 s = q + pv;
    f32x2 m = s * 0.33f;
    f32x2 r = __builtin_elementwise_max(s, m);
    unsigned u;
    asm("v_cvt_pk_bf16_f32 %0, %1, %2" : "=v"(u) : "v"(r.x), "v"(r.y));
    return u;
}
__device__ __forceinline__ unsigned pk_bf16(float a, float b) {
    unsigned u;
    asm("v_cvt_pk_bf16_f32 %0, %1, %2" : "=v"(u) : "v"(a), "v"(b));
    return u;
}

// async global->LDS, 16B per lane. LDS base must be wave-uniform; each lane
// deposits its 16B at base + lane*16 (guide: m97 pattern, width=16).
__device__ __forceinline__ void gload_lds16(const void* g, void* l) {
    __builtin_amdgcn_global_load_lds(
        (const __attribute__((address_space(1))) unsigned*)g,
        (__attribute__((address_space(3))) unsigned*)l,
        16, 0, 0);
}

union FragU { s16x8 v; uint4 q; unsigned w[4]; };

// ------------------------------------------------------------------
// Kernel F (fused front stage), 2688 blocks x 256 thr, role by bid:
//   [0,1536)    : f32->bf16 converts (w2a, w2b, e2n_w)
//   [1536,2560) : A1 (row-major x, coalesced; 2 r per block)
//   [2560,2624) : B1 tiled (x tile staged coalesced into padded LDS)
//   [2624,2688) : adjacency bitmasks + rdeg + nodes_raw zeroing
// ------------------------------------------------------------------
__global__ __launch_bounds__(256) void k_front(
    const float* __restrict__ x,
    const float* __restrict__ w2a, unsigned short* __restrict__ w2aM,
    const float* __restrict__ w2b, unsigned short* __restrict__ w2bM,
    const float* __restrict__ e2nw, unsigned short* __restrict__ e2nwM,
    const float* __restrict__ w1a, const float* __restrict__ b1a,
    const float* __restrict__ w1b, const float* __restrict__ b1b,
    float* __restrict__ A1, float* __restrict__ B1,
    unsigned long long* __restrict__ adjw, float* __restrict__ rdegw,
    float* __restrict__ nodes_raw)
{
    const int bid = blockIdx.x;
    const int tid = TID;

    __shared__ float xr[2][256];     // l1a
    __shared__ float xs[64][36];     // l1b (padded)

    if (bid < 1536) {
        const int which = bid >> 9;
        const int inner = bid & 511;
        const float* s; unsigned short* d; int n4;
        if (which == 0)      { s = w2a;  d = w2aM;  n4 = 2097152; }
        else if (which == 1) { s = w2b;  d = w2bM;  n4 = 2097152; }
        else                 { s = e2nw; d = e2nwM; n4 = 131072; }
        for (int i = inner * 256 + tid; i < n4; i += 131072) {
            float4 v = ((const float4*)s)[i];
            ((uint2*)d)[i] = make_uint2(pk_bf16(v.x, v.y), pk_bf16(v.z, v.w));
        }
    } else if (bid < 2560) {
        const int idx = bid - 1536;
        const int rp = idx & 127, b = idx >> 7;
        const int h = tid >> 7, ctid = tid & 127;
        const int r = rp * 2 + h;
        const float* xb = x + b * 65536;
        xr[h][ctid]       = xb[r * 256 + ctid];
        xr[h][ctid + 128] = xb[r * 256 + ctid + 128];
        __syncthreads();
        float acc = b1a[ctid];
        const float* wr = w1a + ctid * 256;
        #pragma unroll 4
        for (int q = 0; q < 256; q += 8) {
            float4 a = *(const float4*)(wr + q);
            float4 c = *(const float4*)(wr + q + 4);
            acc += xr[h][q + 0] * a.x + xr[h][q + 1] * a.y + xr[h][q + 2] * a.z + xr[h][q + 3] * a.w;
            acc += xr[h][q + 4] * c.x + xr[h][q + 5] * c.y + xr[h][q + 6] * c.z + xr[h][q + 7] * c.w;
        }
        A1[b * 32768 + ctid * 256 + r] = acc;
    } else if (bid < 2624) {
        const int idx = bid - 2560;
        const int jt = idx & 7, b = idx >> 3;
        const int c = tid & 127, jh = tid >> 7;
        const float* xb = x + b * 65536;
        float acc[16];
        #pragma unroll
        for (int jj = 0; jj < 16; ++jj) acc[jj] = 0.0f;
        for (int ch = 0; ch < 4; ++ch) {
            const int i0 = ch * 64;
            {
                const int row = tid >> 2, seg = tid & 3;
                const float* src = xb + (i0 + row) * 256 + jt * 32 + seg * 8;
                float4 a0 = *(const float4*)src;
                float4 a1 = *(const float4*)(src + 4);
                *(float4*)&xs[row][seg * 8]     = a0;
                *(float4*)&xs[row][seg * 8 + 4] = a1;
            }
            __syncthreads();
            const float* wrow = w1b + c * 256 + i0;
            #pragma unroll
            for (int i4 = 0; i4 < 64; i4 += 4) {
                float4 wv = *(const float4*)(wrow + i4);
                #pragma unroll
                for (int u = 0; u < 4; ++u) {
                    const float wsc = (u == 0) ? wv.x : (u == 1) ? wv.y : (u == 2) ? wv.z : wv.w;
                    const float* xrow = &xs[i4 + u][jh * 16];
                    #pragma unroll
                    for (int jj = 0; jj < 16; ++jj)
                        acc[jj] += wsc * xrow[jj];
                }
            }
            __syncthreads();
        }
        const float bias = b1b[c];
        float* outp = B1 + b * 32768 + c * 256 + jt * 32 + jh * 16;
        #pragma unroll
        for (int jj = 0; jj < 16; ++jj) outp[jj] = acc[jj] + bias;
    } else {
        const int idx = bid - 2624;
        nodes_raw[idx * 256 + tid] = 0.0f;
        const int gx = idx & 7, b = idx >> 3;
        const int wv = tid >> 6, lane = tid & 63;
        const int rbase = gx * 32 + wv * 8;
        for (int rr = 0; rr < 8; ++rr) {
            const int row = rbase + rr;
            int d = 0;
            unsigned long long w[4];
            #pragma unroll
            for (int k = 0; k < 4; ++k) {
                float v = x[b * 65536 + row * 256 + k * 64 + lane];
                w[k] = __ballot(v > 0.0f);
                d += __popcll(w[k]);
            }
            if (lane == 0) {
                #pragma unroll
                for (int k = 0; k < 4; ++k) adjw[(b * 256 + row) * 4 + k] = w[k];
                rdegw[b * 256 + row] = d ? 1.0f / (float)d : 0.0f;
            }
        }
    }
}

// ------------------------------------------------------------------
// Kernel 2: partial[s,bw,p,r] = sum_{c in slice16, q} lrelu(P[c,r]+Q[c,q]) * W[p,c,q]
// 512 blocks x 256 thr (4 waves). Block tile 256p x 64r; 128 steps of 32k.
// Wave tile 64p x 64r (af[4], acc[4][4], 16 MFMA/step).
// W staged via ASYNC global_load_lds (m97 pattern) into a frag-major LDS
// DOUBLE BUFFER (layout = round-7's, harness-verified):
//   wave w, chunk u: one global_load_lds writes LDS slots u*256+w*64+lane
//   (lane-linear 16B, wave-uniform base — the HW requirement), sourcing
//   per-lane global addr Wg (row w*16+(lane&15), kchunk (lane>>4)&3).
//   read: af[pf] = Wl[cur][(wave*4+pf)*64+lane] — lane-linear, 0 conflicts.
// Schedule (ONE barrier/step): issue t+1 DMA into Wl[nxt] -> consume Wl[cur]
// (ds_read af + lane-local H pack + 16 MFMA) -> __syncthreads (its implicit
// vmcnt(0) drain lands the DMA, which had the whole consume phase to fly).
// No register round-trip, so the compiler cannot collapse the prefetch
// (rounds 2-3: reg-path collapsed, VGPR=52; rounds 5/7: reg->LDS commit
// drained at step top = exposed latency, 318-346 us).
// Hazards: write-nxt vs read-cur = disjoint buffers; barrier fences
// write-nxt -> read-nxt and read-cur -> overwrite-cur(t+1).
// XCD-aware decode keeps 2 W slices (4 MB) per XCD L2.
// ------------------------------------------------------------------
__global__ __launch_bounds__(256) void k_e2e(
    const float* __restrict__ A1, const float* __restrict__ B1,
    const unsigned short* __restrict__ w2aM, const unsigned short* __restrict__ w2bM,
    float* __restrict__ part)
{
    const int bid = blockIdx.x;
    const int xcd = bid & 7, tt = bid >> 3;       // 512 blocks
    const int hi = tt >> 5, inner = tt & 31;      // hi 0..1
    const int slice = xcd + 8 * hi;               // 0..15 = (s,which)
    const int s = slice >> 1, which = slice & 1;
    const int rt = inner >> 3, b = inner & 7;     // rt 0..3, b 0..7
    const int bw = b * 2 + which;

    const float* P = (which ? B1 : A1) + b * 32768;
    const float* Q = (which ? A1 : B1) + b * 32768;
    const unsigned short* W = which ? w2bM : w2aM;
    const int c0 = s * 16, r0 = rt * 64;

    __shared__ float Qs[16][256];    // 16 KB
    __shared__ float Ps[16][64];     // 4 KB
    __shared__ uint4 Wl[2][1024];    // 2 x 16 KB, frag-major panels

    const int tid = TID;
    const int wave = tid >> 6, lane = tid & 63, quad = lane >> 4, l16 = lane & 15;

    // ---- stage Qs / Ps ----
    {
        const float4* Qg = (const float4*)(Q + c0 * 256);
        float4* Qd = (float4*)&Qs[0][0];
        #pragma unroll
        for (int u = 0; u < 4; ++u) Qd[tid + u * 256] = Qg[tid + u * 256];
        const int prow = tid >> 4, pc4 = (tid & 15) * 4;
        *(float4*)&Ps[prow][pc4] = *(const float4*)&P[(c0 + prow) * 256 + r0 + pc4];
    }

    // ---- frag-major W staging source (per-lane global address) ----
    const int srow = ((tid >> 6) << 4) + (tid & 15);   // wave*16 + (tid&15)
    const int skc  = (tid >> 4) & 3;                   // 16B chunk within 64B window
    const unsigned short* Wg = W + (size_t)srow * 32768 + c0 * 256 + skc * 8;

    // ---- prologue: async-stage panel 0 into Wl[0] ----
    #pragma unroll
    for (int u = 0; u < 4; ++u)
        gload_lds16(Wg + (size_t)u * 64 * 32768, &Wl[0][u * 256 + wave * 64]);

    __syncthreads();   // drains vmcnt: Qs/Ps + Wl[0] visible to all waves

    f32x4 acc[4][4] = {};

    for (int t = 0; t < 128; ++t) {
        const int cur = t & 1, nxt = cur ^ 1;

        // ---- issue async DMA for panel t+1 into Wl[nxt] ----
        if (t + 1 < 128) {
            const int cn = (t + 1) >> 3, qn = (t + 1) & 7;
            const unsigned short* src = Wg + cn * 256 + qn * 32;
            #pragma unroll
            for (int u = 0; u < 4; ++u)
                gload_lds16(src + (size_t)u * 64 * 32768, &Wl[nxt][u * 256 + wave * 64]);
        }

        const int c = t >> 3, qc = t & 7;

        // ---- af frags from LDS (frag-major, lane-linear 16B reads) ----
        FragU af[4];
        #pragma unroll
        for (int pf = 0; pf < 4; ++pf)
            af[pf].q = Wl[cur][(wave * 4 + pf) * 64 + lane];

        // ---- lane-local H frags: k = quad*8 + j within this 32-k window ----
        f32x2 qp[4];
        #pragma unroll
        for (int m = 0; m < 4; ++m)
            qp[m] = *(const f32x2*)&Qs[c][qc * 32 + quad * 8 + 2 * m];
        FragU hb[4];
        #pragma unroll
        for (int nf = 0; nf < 4; ++nf) {
            const float pv = Ps[c][nf * 16 + l16];
            hb[nf].w[0] = lrelu_pack(pv, qp[0]);
            hb[nf].w[1] = lrelu_pack(pv, qp[1]);
            hb[nf].w[2] = lrelu_pack(pv, qp[2]);
            hb[nf].w[3] = lrelu_pack(pv, qp[3]);
        }

        // ---- 16 MFMAs ----
        #pragma unroll
        for (int nf = 0; nf < 4; ++nf)
            #pragma unroll
            for (int pf = 0; pf < 4; ++pf)
                acc[pf][nf] = __builtin_amdgcn_mfma_f32_16x16x32_bf16(af[pf].v, hb[nf].v, acc[pf][nf], 0, 0, 0);

        __syncthreads();   // drains vmcnt (panel t+1 landed) + fences cur reads
    }

    float* pb = part + (size_t)(s * 16 + bw) * 65536;
    #pragma unroll
    for (int pf = 0; pf < 4; ++pf)
        #pragma unroll
        for (int nf = 0; nf < 4; ++nf)
            #pragma unroll
            for (int e = 0; e < 4; ++e) {
                int p = wave * 64 + pf * 16 + quad * 4 + e;
                int r = r0 + nf * 16 + l16;
                pb[p * 256 + r] = acc[pf][nf][e];
            }
}

// ------------------------------------------------------------------
// Kernel 2b: A2/B2 = sum_s partial + bias. grid (64, 16), block 256.
// ------------------------------------------------------------------
__global__ __launch_bounds__(256) void k_red(
    const float* __restrict__ part,
    const float* __restrict__ b2a, const float* __restrict__ b2b,
    float* __restrict__ A2, float* __restrict__ B2)
{
    const int bw = blockIdx.y; const int b = bw >> 1, which = bw & 1;
    const int idx = blockIdx.x * 256 + TID;
    const float4* pp = (const float4*)part;
    float4 acc = make_float4(0.f, 0.f, 0.f, 0.f);
    #pragma unroll
    for (int s = 0; s < 8; ++s) {
        float4 v = pp[(size_t)(s * 16 + bw) * 16384 + idx];
        acc.x += v.x; acc.y += v.y; acc.z += v.z; acc.w += v.w;
    }
    const int p = idx >> 6;
    const float bias = (which ? b2b : b2a)[p];
    acc.x += bias; acc.y += bias; acc.z += bias; acc.w += bias;
    float* OUT = (which ? B2 : A2) + b * 65536;
    ((float4*)OUT)[idx] = acc;
}

// ------------------------------------------------------------------
// Kernel 3: nodes_raw[b,i,p] += sum_{c slice,q} lrelu(A2[c,i]+B2[c,q])*e2n_w[p,c,q]
// grid (16 it, 8 b, 8 sn), block 256 (4 waves c-split), prefetched, atomic out.
// ------------------------------------------------------------------
__global__ __launch_bounds__(256) void k_e2n(
    const float* __restrict__ A2, const float* __restrict__ B2,
    const unsigned short* __restrict__ e2nw,
    float* __restrict__ nodes_raw)
{
    const int it = blockIdx.x, b = blockIdx.y, sn = blockIdx.z;
    const int tid = TID, wave = tid >> 6, lane = tid & 63, quad = lane >> 4, l16 = lane & 15;
    const int i0 = it * 16;
    const int c0 = sn * 32 + wave * 8;
    const float* Ab = A2 + b * 65536;
    const float* Bb = B2 + b * 65536;
    const float* Brow0 = Bb + c0 * 256 + quad * 8;
    const unsigned short* Wrow0 = e2nw + (size_t)l16 * 65536 + c0 * 256 + quad * 8;

    f32x4 acc = {};
    FragU af[2];
    f32x2 qp[2][4];
    float pv, pvn;

    if (l16 < 8) af[0].q = *(const uint4*)(Wrow0);
    else         af[0].q = make_uint4(0u, 0u, 0u, 0u);
    #pragma unroll
    for (int k = 0; k < 4; ++k) qp[0][k] = *(const f32x2*)(Brow0 + 2 * k);
    pv = Ab[c0 * 256 + i0 + l16];

    for (int cc = 0; cc < 8; ++cc) {
        #pragma unroll
        for (int q0 = 0; q0 < 8; ++q0) {
            const int cur = q0 & 1, nxt = cur ^ 1;
            const int cn = (q0 == 7) ? cc + 1 : cc;
            const int qn = (q0 + 1) & 7;
            if (cn < 8) {
                if (l16 < 8) af[nxt].q = *(const uint4*)(Wrow0 + cn * 256 + qn * 32);
                else         af[nxt].q = make_uint4(0u, 0u, 0u, 0u);
                #pragma unroll
                for (int k = 0; k < 4; ++k)
                    qp[nxt][k] = *(const f32x2*)(Brow0 + cn * 256 + qn * 32 + 2 * k);
            }
            if (q0 == 4 && cc + 1 < 8) pvn = Ab[(c0 + cc + 1) * 256 + i0 + l16];
            FragU hb;
            hb.w[0] = lrelu_pack(pv, qp[cur][0]);
            hb.w[1] = lrelu_pack(pv, qp[cur][1]);
            hb.w[2] = lrelu_pack(pv, qp[cur][2]);
            hb.w[3] = lrelu_pack(pv, qp[cur][3]);
            acc = __builtin_amdgcn_mfma_f32_16x16x32_bf16(af[cur].v, hb.v, acc, 0, 0, 0);
            if (q0 == 7) pv = pvn;
        }
    }
    __shared__ float red[4][16][16];
    #pragma unroll
    for (int t = 0; t < 4; ++t) red[wave][quad * 4 + t][l16] = acc[t];
    __syncthreads();
    const int row = tid >> 4, col = tid & 15;
    if (row < 8) {
        float ssum = red[0][row][col] + red[1][row][col] + red[2][row][col] + red[3][row][col];
        atomicAdd(&nodes_raw[b * 2048 + (i0 + col) * 8 + row], ssum);
    }
}

// ------------------------------------------------------------------
// Kernel 4: graph/pool/readout/MLP. One block per batch. f32 weights/out.
// ------------------------------------------------------------------
__global__ __launch_bounds__(256) void k_tail(
    const unsigned long long* __restrict__ adjw, const float* __restrict__ rdegw,
    const float* __restrict__ nodes_raw, const float* __restrict__ e2n_b,
    const float* __restrict__ a11_w, const float* __restrict__ a11_b,
    const float* __restrict__ a12_w, const float* __restrict__ a12_b,
    const float* __restrict__ g1_w,  const float* __restrict__ g1_b,
    const float* __restrict__ a21_w, const float* __restrict__ a21_b,
    const float* __restrict__ a22_w, const float* __restrict__ a22_b,
    const float* __restrict__ d1_w,  const float* __restrict__ d1_b,
    const float* __restrict__ d2_w,  const float* __restrict__ d2_b,
    const float* __restrict__ d3_w,  const float* __restrict__ d3_b,
    float* __restrict__ out)
{
    const int b = blockIdx.x;
    const int tid = TID;

    __shared__ unsigned long long adj[256][4];
    __shared__ float nod[256][8];
    __shared__ float rdeg[256];
    __shared__ float md[256];
    __shared__ float w1s[256];
    __shared__ float w2s[256];
    __shared__ int   selflag[256];
    __shared__ int   selidx[128];
    __shared__ float s1v[128];
    __shared__ float out1[128][8];
    __shared__ float aggL[128][8];
    __shared__ float h2L[128][8];
    __shared__ unsigned long long adj1[128][2];
    __shared__ float rdeg1[128];
    __shared__ float tA[128];
    __shared__ float w1t[128];
    __shared__ float w2t[128];
    __shared__ int   sel2flag[128];
    __shared__ int   sel2idx[64];
    __shared__ float s2v[64];
    __shared__ float out2[64][8];
    __shared__ float r1[16], r2[16], zz[16];
    __shared__ float z1[128];
    __shared__ float z2[64];

    if (tid < 128) { selidx[tid] = 0; s1v[tid] = 0.0f; }
    if (tid < 64)  { sel2idx[tid] = 0; s2v[tid] = 0.0f; }

    {
        #pragma unroll
        for (int k = 0; k < 4; ++k) adj[tid][k] = adjw[(b * 256 + tid) * 4 + k];
        rdeg[tid] = rdegw[b * 256 + tid];
        for (int f = 0; f < 8; ++f)
            nod[tid][f] = lrelu_f(nodes_raw[b * 2048 + tid * 8 + f] + e2n_b[f]);
    }
    __syncthreads();
    {
        float s = 0.0f;
        for (int f = 0; f < 8; ++f) s += nod[tid][f] * a11_w[f];
        md[tid] = s * rdeg[tid];
    }
    __syncthreads();
    {
        float s = 0.0f;
        for (int k = 0; k < 4; ++k) {
            unsigned long long m = adj[tid][k];
            while (m) { int j = __builtin_ctzll(m); m &= m - 1; s += md[k * 64 + j]; }
        }
        w1s[tid] = lrelu_f(s + a11_b[0]);
    }
    __syncthreads();
    md[tid] = w1s[tid] * a12_w[0] * rdeg[tid];
    __syncthreads();
    {
        float s = 0.0f;
        for (int k = 0; k < 4; ++k) {
            unsigned long long m = adj[tid][k];
            while (m) { int j = __builtin_ctzll(m); m &= m - 1; s += md[k * 64 + j]; }
        }
        w2s[tid] = 1.0f / (1.0f + expf(-(s + a12_b[0])));
    }
    __syncthreads();
    {
        const float my = w2s[tid];
        int cnt = 0;
        for (int j = 0; j < 256; ++j) {
            float o = w2s[j];
            cnt += (o > my) || (o == my && j < tid);
        }
        selflag[tid] = (cnt < 128) ? 1 : 0;
    }
    __syncthreads();
    if (selflag[tid]) {
        int pos = 0;
        for (int j = 0; j < tid; ++j) pos += selflag[j];
        if (pos < 128) { selidx[pos] = tid; s1v[pos] = w2s[tid]; }
    }
    __syncthreads();
    for (int k = tid; k < 1024; k += 256) {
        int t = k >> 3, f = k & 7;
        out1[t][f] = nod[selidx[t]][f] * (1.0f + s1v[t]);
    }
    __syncthreads();
    if (tid < 16) {
        int f = tid & 7;
        if (tid < 8) {
            float mx = -INFINITY;
            for (int t = 0; t < 128; ++t) mx = fmaxf(mx, out1[t][f]);
            r1[tid] = mx;
        } else {
            float s = 0.0f;
            for (int t = 0; t < 128; ++t) s += out1[t][f];
            r1[tid] = s * (1.0f / 128.0f);
        }
    }
    if (tid < 128) {
        unsigned long long wds[2] = {0ull, 0ull};
        const int gi = selidx[tid];
        for (int u = 0; u < 128; ++u) {
            const int gj = selidx[u];
            unsigned long long bit = (adj[gi][gj >> 6] >> (gj & 63)) & 1ull;
            wds[u >> 6] |= bit << (u & 63);
        }
        adj1[tid][0] = wds[0]; adj1[tid][1] = wds[1];
        int d = __popcll(wds[0]) + __popcll(wds[1]);
        rdeg1[tid] = d ? 1.0f / (float)d : 0.0f;
    }
    __syncthreads();
    {
        const int t = tid >> 1, f0 = (tid & 1) * 4;
        float a0 = 0, a1 = 0, a2 = 0, a3 = 0;
        for (int k = 0; k < 2; ++k) {
            unsigned long long m = adj1[t][k];
            while (m) {
                int u = __builtin_ctzll(m); m &= m - 1;
                int uu = k * 64 + u;
                float rr = rdeg1[uu];
                a0 += out1[uu][f0 + 0] * rr;
                a1 += out1[uu][f0 + 1] * rr;
                a2 += out1[uu][f0 + 2] * rr;
                a3 += out1[uu][f0 + 3] * rr;
            }
        }
        aggL[t][f0 + 0] = a0; aggL[t][f0 + 1] = a1; aggL[t][f0 + 2] = a2; aggL[t][f0 + 3] = a3;
    }
    __syncthreads();
    for (int k = tid; k < 1024; k += 256) {
        int t = k >> 3, fo = k & 7;
        float s = g1_b[fo];
        for (int f = 0; f < 8; ++f) s += aggL[t][f] * g1_w[fo * 8 + f];
        h2L[t][fo] = s;
    }
    __syncthreads();
    if (tid < 128) {
        float s = 0.0f;
        for (int f = 0; f < 8; ++f) s += h2L[tid][f] * a21_w[f];
        tA[tid] = s * rdeg1[tid];
    }
    __syncthreads();
    if (tid < 128) {
        float s = 0.0f;
        for (int k = 0; k < 2; ++k) {
            unsigned long long m = adj1[tid][k];
            while (m) { int u = __builtin_ctzll(m); m &= m - 1; s += tA[k * 64 + u]; }
        }
        w1t[tid] = lrelu_f(s + a21_b[0]);
    }
    __syncthreads();
    if (tid < 128) tA[tid] = w1t[tid] * a22_w[0] * rdeg1[tid];
    __syncthreads();
    if (tid < 128) {
        float s = 0.0f;
        for (int k = 0; k < 2; ++k) {
            unsigned long long m = adj1[tid][k];
            while (m) { int u = __builtin_ctzll(m); m &= m - 1; s += tA[k * 64 + u]; }
        }
        w2t[tid] = 1.0f / (1.0f + expf(-(s + a22_b[0])));
    }
    __syncthreads();
    if (tid < 128) {
        const float my = w2t[tid];
        int cnt = 0;
        for (int u = 0; u < 128; ++u) {
            float o = w2t[u];
            cnt += (o > my) || (o == my && u < tid);
        }
        sel2flag[tid] = (cnt < 64) ? 1 : 0;
    }
    __syncthreads();
    if (tid < 128 && sel2flag[tid]) {
        int pos = 0;
        for (int u = 0; u < tid; ++u) pos += sel2flag[u];
        if (pos < 64) { sel2idx[pos] = tid; s2v[pos] = w2t[tid]; }
    }
    __syncthreads();
    for (int k = tid; k < 512; k += 256) {
        int u = k >> 3, f = k & 7;
        out2[u][f] = h2L[sel2idx[u]][f] * (1.0f + s2v[u]);
    }
    __syncthreads();
    if (tid < 16) {
        int f = tid & 7;
        if (tid < 8) {
            float mx = -INFINITY;
            for (int t = 0; t < 64; ++t) mx = fmaxf(mx, out2[t][f]);
            r2[tid] = mx;
        } else {
            float s = 0.0f;
            for (int t = 0; t < 64; ++t) s += out2[t][f];
            r2[tid] = s * (1.0f / 64.0f);
        }
    }
    __syncthreads();
    if (tid < 16) zz[tid] = r1[tid] + r2[tid];
    __syncthreads();
    if (tid < 128) {
        float s = d1_b[tid];
        for (int k = 0; k < 16; ++k) s += zz[k] * d1_w[tid * 16 + k];
        z1[tid] = lrelu_f(s);
    }
    __syncthreads();
    if (tid < 64) {
        float s = d2_b[tid];
        for (int k = 0; k < 128; ++k) s += z1[k] * d2_w[tid * 128 + k];
        z2[tid] = lrelu_f(s);
    }
    __syncthreads();
    if (tid == 0) {
        float s = d3_b[0];
        for (int k = 0; k < 64; ++k) s += z2[k] * d3_w[k];
        out[b] = s;
    }
}

// ------------------------------------------------------------------
extern "C" void kernel_launch(void* const* d_in, const int* in_sizes, int n_in,
                              void* d_out, int out_size, void* d_ws, size_t ws_size,
                              hipStream_t stream) {
    const float* x     = (const float*)d_in[0];
    const float* w1a   = (const float*)d_in[1];
    const float* b1a   = (const float*)d_in[2];
    const float* w1b   = (const float*)d_in[3];
    const float* b1b   = (const float*)d_in[4];
    const float* w2a   = (const float*)d_in[5];
    const float* b2a   = (const float*)d_in[6];
    const float* w2b   = (const float*)d_in[7];
    const float* b2b   = (const float*)d_in[8];
    const float* e2nw  = (const float*)d_in[9];

    float* ws        = (float*)d_ws;
    float* A1        = ws;                     // 262144
    float* B1        = ws + 262144;            // 262144
    float* A2        = ws + 524288;            // 524288
    float* B2        = ws + 1048576;           // 524288
    float* nodes_raw = ws + 1572864;           // 16384
    float* rdegw     = ws + 1589248;           // 8192 (oversized, 2048 used)
    unsigned long long* adjw = (unsigned long long*)(ws + 1597440); // 8192 ull = 16384 f
    float* part      = ws + 1613824;           // 8388608
    unsigned short* w2aM  = (unsigned short*)(ws + 10002432);            // 8388608 shorts
    unsigned short* w2bM  = w2aM + 8388608;
    unsigned short* e2nwM = w2bM + 8388608;                              // 524288 shorts

    k_front<<<dim3(2688), 256, 0, stream>>>(
        x, w2a, w2aM, w2b, w2bM, e2nw, e2nwM,
        w1a, b1a, w1b, b1b, A1, B1, adjw, rdegw, nodes_raw);
    k_e2e<<<dim3(512), 256, 0, stream>>>(A1, B1, w2aM, w2bM, part);
    k_red<<<dim3(64, 16), 256, 0, stream>>>(part, b2a, b2b, A2, B2);
    k_e2n<<<dim3(16, 8, 8), 256, 0, stream>>>(A2, B2, e2nwM, nodes_raw);
    k_tail<<<dim3(8), 256, 0, stream>>>(adjw, rdegw, nodes_raw, (const float*)d_in[10],
        (const float*)d_in[11], (const float*)d_in[12], (const float*)d_in[13], (const float*)d_in[14],
        (const float*)d_in[15], (const float*)d_in[16], (const float*)d_in[17], (const float*)d_in[18],
        (const float*)d_in[19], (const float*)d_in[20], (const float*)d_in[21], (const float*)d_in[22],
        (const float*)d_in[23], (const float*)d_in[24], (const float*)d_in[25], (const float*)d_in[26],
        (float*)d_out);
}

// Round 11
// 427.021 us; speedup vs baseline: 1.0209x; 1.0209x over previous
//
#include <hip/hip_runtime.h>

typedef short s16x8 __attribute__((ext_vector_type(8)));
typedef float f32x4 __attribute__((ext_vector_type(4)));
typedef float f32x2 __attribute__((ext_vector_type(2)));

#define TID threadIdx.x

__device__ __forceinline__ float lrelu_f(float x) { return fmaxf(x, 0.33f * x); }

// lrelu(pv+q.x), lrelu(pv+q.y) -> packed bf16x2 using HW v_cvt_pk_bf16_f32
__device__ __forceinline__ unsigned lrelu_pack(float pv, f32x2 q) {
    f32x2 s = q + pv;
    f32x2 m = s * 0.33f;
    f32x2 r = __builtin_elementwise_max(s, m);
    unsigned u;
    asm("v_cvt_pk_bf16_f32 %0, %1, %2" : "=v"(u) : "v"(r.x), "v"(r.y));
    return u;
}
__device__ __forceinline__ unsigned pk_bf16(float a, float b) {
    unsigned u;
    asm("v_cvt_pk_bf16_f32 %0, %1, %2" : "=v"(u) : "v"(a), "v"(b));
    return u;
}

union FragU { s16x8 v; uint4 q; unsigned w[4]; };

// Pin a 16B fragment's registers live at this program point. Forces the
// feeding load to be issued earlier and COMPLETED by here (waitcnt lands
// here, after the MFMA shadow) and forbids the compiler's load-sinking /
// rematerialization (rounds 2-3/9: VGPR=52 proved prefetches were
// discarded and reloaded at use, exposing full L2 latency every step).
#define PIN(x) asm volatile("" : "+v"((x).w[0]), "+v"((x).w[1]), "+v"((x).w[2]), "+v"((x).w[3]))

// ------------------------------------------------------------------
// Kernel F (fused front stage), 2688 blocks x 256 thr, role by bid:
//   [0,1536)    : f32->bf16 converts (w2a, w2b, e2n_w)
//   [1536,2560) : A1 (row-major x, coalesced; 2 r per block)
//   [2560,2624) : B1 tiled (x tile staged coalesced into padded LDS)
//   [2624,2688) : adjacency bitmasks + rdeg + nodes_raw zeroing
// ------------------------------------------------------------------
__global__ __launch_bounds__(256) void k_front(
    const float* __restrict__ x,
    const float* __restrict__ w2a, unsigned short* __restrict__ w2aM,
    const float* __restrict__ w2b, unsigned short* __restrict__ w2bM,
    const float* __restrict__ e2nw, unsigned short* __restrict__ e2nwM,
    const float* __restrict__ w1a, const float* __restrict__ b1a,
    const float* __restrict__ w1b, const float* __restrict__ b1b,
    float* __restrict__ A1, float* __restrict__ B1,
    unsigned long long* __restrict__ adjw, float* __restrict__ rdegw,
    float* __restrict__ nodes_raw)
{
    const int bid = blockIdx.x;
    const int tid = TID;

    __shared__ float xr[2][256];     // l1a
    __shared__ float xs[64][36];     // l1b (padded)

    if (bid < 1536) {
        const int which = bid >> 9;
        const int inner = bid & 511;
        const float* s; unsigned short* d; int n4;
        if (which == 0)      { s = w2a;  d = w2aM;  n4 = 2097152; }
        else if (which == 1) { s = w2b;  d = w2bM;  n4 = 2097152; }
        else                 { s = e2nw; d = e2nwM; n4 = 131072; }
        for (int i = inner * 256 + tid; i < n4; i += 131072) {
            float4 v = ((const float4*)s)[i];
            ((uint2*)d)[i] = make_uint2(pk_bf16(v.x, v.y), pk_bf16(v.z, v.w));
        }
    } else if (bid < 2560) {
        const int idx = bid - 1536;
        const int rp = idx & 127, b = idx >> 7;
        const int h = tid >> 7, ctid = tid & 127;
        const int r = rp * 2 + h;
        const float* xb = x + b * 65536;
        xr[h][ctid]       = xb[r * 256 + ctid];
        xr[h][ctid + 128] = xb[r * 256 + ctid + 128];
        __syncthreads();
        float acc = b1a[ctid];
        const float* wr = w1a + ctid * 256;
        #pragma unroll 4
        for (int q = 0; q < 256; q += 8) {
            float4 a = *(const float4*)(wr + q);
            float4 c = *(const float4*)(wr + q + 4);
            acc += xr[h][q + 0] * a.x + xr[h][q + 1] * a.y + xr[h][q + 2] * a.z + xr[h][q + 3] * a.w;
            acc += xr[h][q + 4] * c.x + xr[h][q + 5] * c.y + xr[h][q + 6] * c.z + xr[h][q + 7] * c.w;
        }
        A1[b * 32768 + ctid * 256 + r] = acc;
    } else if (bid < 2624) {
        const int idx = bid - 2560;
        const int jt = idx & 7, b = idx >> 3;
        const int c = tid & 127, jh = tid >> 7;
        const float* xb = x + b * 65536;
        float acc[16];
        #pragma unroll
        for (int jj = 0; jj < 16; ++jj) acc[jj] = 0.0f;
        for (int ch = 0; ch < 4; ++ch) {
            const int i0 = ch * 64;
            {
                const int row = tid >> 2, seg = tid & 3;
                const float* src = xb + (i0 + row) * 256 + jt * 32 + seg * 8;
                float4 a0 = *(const float4*)src;
                float4 a1 = *(const float4*)(src + 4);
                *(float4*)&xs[row][seg * 8]     = a0;
                *(float4*)&xs[row][seg * 8 + 4] = a1;
            }
            __syncthreads();
            const float* wrow = w1b + c * 256 + i0;
            #pragma unroll
            for (int i4 = 0; i4 < 64; i4 += 4) {
                float4 wv = *(const float4*)(wrow + i4);
                #pragma unroll
                for (int u = 0; u < 4; ++u) {
                    const float wsc = (u == 0) ? wv.x : (u == 1) ? wv.y : (u == 2) ? wv.z : wv.w;
                    const float* xrow = &xs[i4 + u][jh * 16];
                    #pragma unroll
                    for (int jj = 0; jj < 16; ++jj)
                        acc[jj] += wsc * xrow[jj];
                }
            }
            __syncthreads();
        }
        const float bias = b1b[c];
        float* outp = B1 + b * 32768 + c * 256 + jt * 32 + jh * 16;
        #pragma unroll
        for (int jj = 0; jj < 16; ++jj) outp[jj] = acc[jj] + bias;
    } else {
        const int idx = bid - 2624;
        nodes_raw[idx * 256 + tid] = 0.0f;
        const int gx = idx & 7, b = idx >> 3;
        const int wv = tid >> 6, lane = tid & 63;
        const int rbase = gx * 32 + wv * 8;
        for (int rr = 0; rr < 8; ++rr) {
            const int row = rbase + rr;
            int d = 0;
            unsigned long long w[4];
            #pragma unroll
            for (int k = 0; k < 4; ++k) {
                float v = x[b * 65536 + row * 256 + k * 64 + lane];
                w[k] = __ballot(v > 0.0f);
                d += __popcll(w[k]);
            }
            if (lane == 0) {
                #pragma unroll
                for (int k = 0; k < 4; ++k) adjw[(b * 256 + row) * 4 + k] = w[k];
                rdegw[b * 256 + row] = d ? 1.0f / (float)d : 0.0f;
            }
        }
    }
}

// ------------------------------------------------------------------
// Kernel 2: partial[s,bw,p,r] = sum_{c in slice16, q} lrelu(P[c,r]+Q[c,q]) * W[p,c,q]
// ROUND-3 STRUCTURE (passed, 136 us) + PIN() on the prefetched af/hbf
// fragments after the MFMA block. The pin forbids load-sinking (the one
// defect the VGPR=52 count proved) and gives every W global load and H
// ds_read a full MFMA-block latency shadow.
// 1-D grid 512 blocks, 512 threads = 8 waves, each wave owns 32 p-rows.
// r-tile 64 per block. LDS 52 KB -> 2 blocks/CU (4 waves/SIMD).
// XCD-aware decode keeps 2 W slices (4 MB) per XCD L2.
// ------------------------------------------------------------------
__global__ __launch_bounds__(512, 4) void k_e2e(
    const float* __restrict__ A1, const float* __restrict__ B1,
    const unsigned short* __restrict__ w2aM, const unsigned short* __restrict__ w2bM,
    float* __restrict__ part)
{
    const int bid = blockIdx.x;
    const int xcd = bid & 7, tt = bid >> 3;       // 512 blocks
    const int hi = tt >> 5, inner = tt & 31;      // hi 0..1
    const int slice = xcd + 8 * hi;               // 0..15 = (s,which)
    const int s = slice >> 1, which = slice & 1;
    const int rt = inner >> 3, b = inner & 7;     // rt 0..3, b 0..7
    const int bw = b * 2 + which;

    const float* P = (which ? B1 : A1) + b * 32768;
    const float* Q = (which ? A1 : B1) + b * 32768;
    const unsigned short* W = which ? w2bM : w2aM;
    const int c0 = s * 16, r0 = rt * 64;

    __shared__ float Qs[16][256];   // 16 KB
    __shared__ float Ps[16][64];    // 4 KB
    __shared__ uint4 Hs[2048];      // 32 KB

    const int tid = TID;
    const int wave = tid >> 6, lane = tid & 63, quad = lane >> 4, l16 = lane & 15;
    const int pbase = wave * 32;

    {
        const float4* Qg = (const float4*)(Q + c0 * 256);
        float4* Qd = (float4*)&Qs[0][0];
        Qd[tid]       = Qg[tid];
        Qd[tid + 512] = Qg[tid + 512];
        int row = tid >> 5, c2 = (tid & 31) * 2;
        *(float2*)&Ps[row][c2] = *(const float2*)&P[(c0 + row) * 256 + r0 + c2];
    }
    __syncthreads();

    // ---- produce H(c=0): wave w owns q-chunk qc=w ----
    {
        const int qb = wave * 32 + quad * 8;
        f32x2 qp0 = *(const f32x2*)&Qs[0][qb + 0];
        f32x2 qp1 = *(const f32x2*)&Qs[0][qb + 2];
        f32x2 qp2 = *(const f32x2*)&Qs[0][qb + 4];
        f32x2 qp3 = *(const f32x2*)&Qs[0][qb + 6];
        #pragma unroll
        for (int rf = 0; rf < 4; ++rf) {
            float pv = Ps[0][rf * 16 + l16];
            uint4 u;
            u.x = lrelu_pack(pv, qp0);
            u.y = lrelu_pack(pv, qp1);
            u.z = lrelu_pack(pv, qp2);
            u.w = lrelu_pack(pv, qp3);
            Hs[(wave * 4 + rf) * 64 + lane] = u;
        }
    }

    f32x4 acc[2][4] = {};
    const unsigned short* Wrow[2];
    #pragma unroll
    for (int pf = 0; pf < 2; ++pf)
        Wrow[pf] = W + (size_t)(pbase + pf * 16 + l16) * 32768 + c0 * 256 + quad * 8;

    FragU af[2][2];
    #pragma unroll
    for (int pf = 0; pf < 2; ++pf) af[0][pf].q = *(const uint4*)(Wrow[pf]);

    __syncthreads();   // Hs(0) ready

    for (int c = 0; c < 16; ++c) {
        FragU hbf[2][4];
        #pragma unroll
        for (int nf = 0; nf < 4; ++nf)
            hbf[0][nf].q = Hs[nf * 64 + lane];

        #pragma unroll
        for (int q0 = 0; q0 < 8; ++q0) {
            const int cur = q0 & 1, nxt = cur ^ 1;
            // W prefetch for next step (crosses channel boundary freely)
            const int cn = c + ((q0 + 1) >> 3), qn = (q0 + 1) & 7;
            if (cn < 16) {
                #pragma unroll
                for (int pf = 0; pf < 2; ++pf)
                    af[nxt][pf].q = *(const uint4*)(Wrow[pf] + cn * 256 + qn * 32);
            }
            // H frag prefetch for next qc (same channel only)
            if (q0 < 7) {
                #pragma unroll
                for (int nf = 0; nf < 4; ++nf)
                    hbf[nxt][nf].q = Hs[((q0 + 1) * 4 + nf) * 64 + lane];
            }
            // 8 MFMAs
            #pragma unroll
            for (int nf = 0; nf < 4; ++nf)
                #pragma unroll
                for (int pf = 0; pf < 2; ++pf)
                    acc[pf][nf] = __builtin_amdgcn_mfma_f32_16x16x32_bf16(af[cur][pf].v, hbf[cur][nf].v, acc[pf][nf], 0, 0, 0);
            // Pin prefetched fragments live HERE (after the MFMA shadow):
            // loads must complete by this point and stay in registers for
            // next step's use — the compiler can no longer sink them.
            if (cn < 16) { PIN(af[nxt][0]); PIN(af[nxt][1]); }
            if (q0 < 7)  { PIN(hbf[nxt][0]); PIN(hbf[nxt][1]); PIN(hbf[nxt][2]); PIN(hbf[nxt][3]); }
        }
        __syncthreads();   // done reading Hs(c)
        if (c + 1 < 16) {
            const int qb = wave * 32 + quad * 8;
            f32x2 qp0 = *(const f32x2*)&Qs[c + 1][qb + 0];
            f32x2 qp1 = *(const f32x2*)&Qs[c + 1][qb + 2];
            f32x2 qp2 = *(const f32x2*)&Qs[c + 1][qb + 4];
            f32x2 qp3 = *(const f32x2*)&Qs[c + 1][qb + 6];
            #pragma unroll
            for (int rf = 0; rf < 4; ++rf) {
                float pv = Ps[c + 1][rf * 16 + l16];
                uint4 u;
                u.x = lrelu_pack(pv, qp0);
                u.y = lrelu_pack(pv, qp1);
                u.z = lrelu_pack(pv, qp2);
                u.w = lrelu_pack(pv, qp3);
                Hs[(wave * 4 + rf) * 64 + lane] = u;
            }
            __syncthreads();   // Hs(c+1) ready
        }
    }

    float* pb = part + (size_t)(s * 16 + bw) * 65536;
    #pragma unroll
    for (int pf = 0; pf < 2; ++pf)
        #pragma unroll
        for (int nf = 0; nf < 4; ++nf)
            #pragma unroll
            for (int t = 0; t < 4; ++t) {
                int p = pbase + pf * 16 + quad * 4 + t;
                int r = r0 + nf * 16 + l16;
                pb[p * 256 + r] = acc[pf][nf][t];
            }
}

// ------------------------------------------------------------------
// Kernel 2b: A2/B2 = sum_s partial + bias. grid (64, 16), block 256.
// ------------------------------------------------------------------
__global__ __launch_bounds__(256) void k_red(
    const float* __restrict__ part,
    const float* __restrict__ b2a, const float* __restrict__ b2b,
    float* __restrict__ A2, float* __restrict__ B2)
{
    const int bw = blockIdx.y; const int b = bw >> 1, which = bw & 1;
    const int idx = blockIdx.x * 256 + TID;
    const float4* pp = (const float4*)part;
    float4 acc = make_float4(0.f, 0.f, 0.f, 0.f);
    #pragma unroll
    for (int s = 0; s < 8; ++s) {
        float4 v = pp[(size_t)(s * 16 + bw) * 16384 + idx];
        acc.x += v.x; acc.y += v.y; acc.z += v.z; acc.w += v.w;
    }
    const int p = idx >> 6;
    const float bias = (which ? b2b : b2a)[p];
    acc.x += bias; acc.y += bias; acc.z += bias; acc.w += bias;
    float* OUT = (which ? B2 : A2) + b * 65536;
    ((float4*)OUT)[idx] = acc;
}

// ------------------------------------------------------------------
// Kernel 3: nodes_raw[b,i,p] += sum_{c slice,q} lrelu(A2[c,i]+B2[c,q])*e2n_w[p,c,q]
// grid (16 it, 8 b, 8 sn), block 256 (4 waves c-split), prefetched, atomic out.
// ------------------------------------------------------------------
__global__ __launch_bounds__(256) void k_e2n(
    const float* __restrict__ A2, const float* __restrict__ B2,
    const unsigned short* __restrict__ e2nw,
    float* __restrict__ nodes_raw)
{
    const int it = blockIdx.x, b = blockIdx.y, sn = blockIdx.z;
    const int tid = TID, wave = tid >> 6, lane = tid & 63, quad = lane >> 4, l16 = lane & 15;
    const int i0 = it * 16;
    const int c0 = sn * 32 + wave * 8;
    const float* Ab = A2 + b * 65536;
    const float* Bb = B2 + b * 65536;
    const float* Brow0 = Bb + c0 * 256 + quad * 8;
    const unsigned short* Wrow0 = e2nw + (size_t)l16 * 65536 + c0 * 256 + quad * 8;

    f32x4 acc = {};
    FragU af[2];
    f32x2 qp[2][4];
    float pv, pvn;

    if (l16 < 8) af[0].q = *(const uint4*)(Wrow0);
    else         af[0].q = make_uint4(0u, 0u, 0u, 0u);
    #pragma unroll
    for (int k = 0; k < 4; ++k) qp[0][k] = *(const f32x2*)(Brow0 + 2 * k);
    pv = Ab[c0 * 256 + i0 + l16];

    for (int cc = 0; cc < 8; ++cc) {
        #pragma unroll
        for (int q0 = 0; q0 < 8; ++q0) {
            const int cur = q0 & 1, nxt = cur ^ 1;
            const int cn = (q0 == 7) ? cc + 1 : cc;
            const int qn = (q0 + 1) & 7;
            if (cn < 8) {
                if (l16 < 8) af[nxt].q = *(const uint4*)(Wrow0 + cn * 256 + qn * 32);
                else         af[nxt].q = make_uint4(0u, 0u, 0u, 0u);
                #pragma unroll
                for (int k = 0; k < 4; ++k)
                    qp[nxt][k] = *(const f32x2*)(Brow0 + cn * 256 + qn * 32 + 2 * k);
            }
            if (q0 == 4 && cc + 1 < 8) pvn = Ab[(c0 + cc + 1) * 256 + i0 + l16];
            FragU hb;
            hb.w[0] = lrelu_pack(pv, qp[cur][0]);
            hb.w[1] = lrelu_pack(pv, qp[cur][1]);
            hb.w[2] = lrelu_pack(pv, qp[cur][2]);
            hb.w[3] = lrelu_pack(pv, qp[cur][3]);
            acc = __builtin_amdgcn_mfma_f32_16x16x32_bf16(af[cur].v, hb.v, acc, 0, 0, 0);
            if (q0 == 7) pv = pvn;
        }
    }
    __shared__ float red[4][16][16];
    #pragma unroll
    for (int t = 0; t < 4; ++t) red[wave][quad * 4 + t][l16] = acc[t];
    __syncthreads();
    const int row = tid >> 4, col = tid & 15;
    if (row < 8) {
        float ssum = red[0][row][col] + red[1][row][col] + red[2][row][col] + red[3][row][col];
        atomicAdd(&nodes_raw[b * 2048 + (i0 + col) * 8 + row], ssum);
    }
}

// ------------------------------------------------------------------
// Kernel 4: graph/pool/readout/MLP. One block per batch. f32 weights/out.
// ------------------------------------------------------------------
__global__ __launch_bounds__(256) void k_tail(
    const unsigned long long* __restrict__ adjw, const float* __restrict__ rdegw,
    const float* __restrict__ nodes_raw, const float* __restrict__ e2n_b,
    const float* __restrict__ a11_w, const float* __restrict__ a11_b,
    const float* __restrict__ a12_w, const float* __restrict__ a12_b,
    const float* __restrict__ g1_w,  const float* __restrict__ g1_b,
    const float* __restrict__ a21_w, const float* __restrict__ a21_b,
    const float* __restrict__ a22_w, const float* __restrict__ a22_b,
    const float* __restrict__ d1_w,  const float* __restrict__ d1_b,
    const float* __restrict__ d2_w,  const float* __restrict__ d2_b,
    const float* __restrict__ d3_w,  const float* __restrict__ d3_b,
    float* __restrict__ out)
{
    const int b = blockIdx.x;
    const int tid = TID;

    __shared__ unsigned long long adj[256][4];
    __shared__ float nod[256][8];
    __shared__ float rdeg[256];
    __shared__ float md[256];
    __shared__ float w1s[256];
    __shared__ float w2s[256];
    __shared__ int   selflag[256];
    __shared__ int   selidx[128];
    __shared__ float s1v[128];
    __shared__ float out1[128][8];
    __shared__ float aggL[128][8];
    __shared__ float h2L[128][8];
    __shared__ unsigned long long adj1[128][2];
    __shared__ float rdeg1[128];
    __shared__ float tA[128];
    __shared__ float w1t[128];
    __shared__ float w2t[128];
    __shared__ int   sel2flag[128];
    __shared__ int   sel2idx[64];
    __shared__ float s2v[64];
    __shared__ float out2[64][8];
    __shared__ float r1[16], r2[16], zz[16];
    __shared__ float z1[128];
    __shared__ float z2[64];

    if (tid < 128) { selidx[tid] = 0; s1v[tid] = 0.0f; }
    if (tid < 64)  { sel2idx[tid] = 0; s2v[tid] = 0.0f; }

    {
        #pragma unroll
        for (int k = 0; k < 4; ++k) adj[tid][k] = adjw[(b * 256 + tid) * 4 + k];
        rdeg[tid] = rdegw[b * 256 + tid];
        for (int f = 0; f < 8; ++f)
            nod[tid][f] = lrelu_f(nodes_raw[b * 2048 + tid * 8 + f] + e2n_b[f]);
    }
    __syncthreads();
    {
        float s = 0.0f;
        for (int f = 0; f < 8; ++f) s += nod[tid][f] * a11_w[f];
        md[tid] = s * rdeg[tid];
    }
    __syncthreads();
    {
        float s = 0.0f;
        for (int k = 0; k < 4; ++k) {
            unsigned long long m = adj[tid][k];
            while (m) { int j = __builtin_ctzll(m); m &= m - 1; s += md[k * 64 + j]; }
        }
        w1s[tid] = lrelu_f(s + a11_b[0]);
    }
    __syncthreads();
    md[tid] = w1s[tid] * a12_w[0] * rdeg[tid];
    __syncthreads();
    {
        float s = 0.0f;
        for (int k = 0; k < 4; ++k) {
            unsigned long long m = adj[tid][k];
            while (m) { int j = __builtin_ctzll(m); m &= m - 1; s += md[k * 64 + j]; }
        }
        w2s[tid] = 1.0f / (1.0f + expf(-(s + a12_b[0])));
    }
    __syncthreads();
    {
        const float my = w2s[tid];
        int cnt = 0;
        for (int j = 0; j < 256; ++j) {
            float o = w2s[j];
            cnt += (o > my) || (o == my && j < tid);
        }
        selflag[tid] = (cnt < 128) ? 1 : 0;
    }
    __syncthreads();
    if (selflag[tid]) {
        int pos = 0;
        for (int j = 0; j < tid; ++j) pos += selflag[j];
        if (pos < 128) { selidx[pos] = tid; s1v[pos] = w2s[tid]; }
    }
    __syncthreads();
    for (int k = tid; k < 1024; k += 256) {
        int t = k >> 3, f = k & 7;
        out1[t][f] = nod[selidx[t]][f] * (1.0f + s1v[t]);
    }
    __syncthreads();
    if (tid < 16) {
        int f = tid & 7;
        if (tid < 8) {
            float mx = -INFINITY;
            for (int t = 0; t < 128; ++t) mx = fmaxf(mx, out1[t][f]);
            r1[tid] = mx;
        } else {
            float s = 0.0f;
            for (int t = 0; t < 128; ++t) s += out1[t][f];
            r1[tid] = s * (1.0f / 128.0f);
        }
    }
    if (tid < 128) {
        unsigned long long wds[2] = {0ull, 0ull};
        const int gi = selidx[tid];
        for (int u = 0; u < 128; ++u) {
            const int gj = selidx[u];
            unsigned long long bit = (adj[gi][gj >> 6] >> (gj & 63)) & 1ull;
            wds[u >> 6] |= bit << (u & 63);
        }
        adj1[tid][0] = wds[0]; adj1[tid][1] = wds[1];
        int d = __popcll(wds[0]) + __popcll(wds[1]);
        rdeg1[tid] = d ? 1.0f / (float)d : 0.0f;
    }
    __syncthreads();
    {
        const int t = tid >> 1, f0 = (tid & 1) * 4;
        float a0 = 0, a1 = 0, a2 = 0, a3 = 0;
        for (int k = 0; k < 2; ++k) {
            unsigned long long m = adj1[t][k];
            while (m) {
                int u = __builtin_ctzll(m); m &= m - 1;
                int uu = k * 64 + u;
                float rr = rdeg1[uu];
                a0 += out1[uu][f0 + 0] * rr;
                a1 += out1[uu][f0 + 1] * rr;
                a2 += out1[uu][f0 + 2] * rr;
                a3 += out1[uu][f0 + 3] * rr;
            }
        }
        aggL[t][f0 + 0] = a0; aggL[t][f0 + 1] = a1; aggL[t][f0 + 2] = a2; aggL[t][f0 + 3] = a3;
    }
    __syncthreads();
    for (int k = tid; k < 1024; k += 256) {
        int t = k >> 3, fo = k & 7;
        float s = g1_b[fo];
        for (int f = 0; f < 8; ++f) s += aggL[t][f] * g1_w[fo * 8 + f];
        h2L[t][fo] = s;
    }
    __syncthreads();
    if (tid < 128) {
        float s = 0.0f;
        for (int f = 0; f < 8; ++f) s += h2L[tid][f] * a21_w[f];
        tA[tid] = s * rdeg1[tid];
    }
    __syncthreads();
    if (tid < 128) {
        float s = 0.0f;
        for (int k = 0; k < 2; ++k) {
            unsigned long long m = adj1[tid][k];
            while (m) { int u = __builtin_ctzll(m); m &= m - 1; s += tA[k * 64 + u]; }
        }
        w1t[tid] = lrelu_f(s + a21_b[0]);
    }
    __syncthreads();
    if (tid < 128) tA[tid] = w1t[tid] * a22_w[0] * rdeg1[tid];
    __syncthreads();
    if (tid < 128) {
        float s = 0.0f;
        for (int k = 0; k < 2; ++k) {
            unsigned long long m = adj1[tid][k];
            while (m) { int u = __builtin_ctzll(m); m &= m - 1; s += tA[k * 64 + u]; }
        }
        w2t[tid] = 1.0f / (1.0f + expf(-(s + a22_b[0])));
    }
    __syncthreads();
    if (tid < 128) {
        const float my = w2t[tid];
        int cnt = 0;
        for (int u = 0; u < 128; ++u) {
            float o = w2t[u];
            cnt += (o > my) || (o == my && u < tid);
        }
        sel2flag[tid] = (cnt < 64) ? 1 : 0;
    }
    __syncthreads();
    if (tid < 128 && sel2flag[tid]) {
        int pos = 0;
        for (int u = 0; u < tid; ++u) pos += sel2flag[u];
        if (pos < 64) { sel2idx[pos] = tid; s2v[pos] = w2t[tid]; }
    }
    __syncthreads();
    for (int k = tid; k < 512; k += 256) {
        int u = k >> 3, f = k & 7;
        out2[u][f] = h2L[sel2idx[u]][f] * (1.0f + s2v[u]);
    }
    __syncthreads();
    if (tid < 16) {
        int f = tid & 7;
        if (tid < 8) {
            float mx = -INFINITY;
            for (int t = 0; t < 64; ++t) mx = fmaxf(mx, out2[t][f]);
            r2[tid] = mx;
        } else {
            float s = 0.0f;
            for (int t = 0; t < 64; ++t) s += out2[t][f];
            r2[tid] = s * (1.0f / 64.0f);
        }
    }
    __syncthreads();
    if (tid < 16) zz[tid] = r1[tid] + r2[tid];
    __syncthreads();
    if (tid < 128) {
        float s = d1_b[tid];
        for (int k = 0; k < 16; ++k) s += zz[k] * d1_w[tid * 16 + k];
        z1[tid] = lrelu_f(s);
    }
    __syncthreads();
    if (tid < 64) {
        float s = d2_b[tid];
        for (int k = 0; k < 128; ++k) s += z1[k] * d2_w[tid * 128 + k];
        z2[tid] = lrelu_f(s);
    }
    __syncthreads();
    if (tid == 0) {
        float s = d3_b[0];
        for (int k = 0; k < 64; ++k) s += z2[k] * d3_w[k];
        out[b] = s;
    }
}

// ------------------------------------------------------------------
extern "C" void kernel_launch(void* const* d_in, const int* in_sizes, int n_in,
                              void* d_out, int out_size, void* d_ws, size_t ws_size,
                              hipStream_t stream) {
    const float* x     = (const float*)d_in[0];
    const float* w1a   = (const float*)d_in[1];
    const float* b1a   = (const float*)d_in[2];
    const float* w1b   = (const float*)d_in[3];
    const float* b1b   = (const float*)d_in[4];
    const float* w2a   = (const float*)d_in[5];
    const float* b2a   = (const float*)d_in[6];
    const float* w2b   = (const float*)d_in[7];
    const float* b2b   = (const float*)d_in[8];
    const float* e2nw  = (const float*)d_in[9];

    float* ws        = (float*)d_ws;
    float* A1        = ws;                     // 262144
    float* B1        = ws + 262144;            // 262144
    float* A2        = ws + 524288;            // 524288
    float* B2        = ws + 1048576;           // 524288
    float* nodes_raw = ws + 1572864;           // 16384
    float* rdegw     = ws + 1589248;           // 8192 (oversized, 2048 used)
    unsigned long long* adjw = (unsigned long long*)(ws + 1597440); // 8192 ull = 16384 f
    float* part      = ws + 1613824;           // 8388608
    unsigned short* w2aM  = (unsigned short*)(ws + 10002432);            // 8388608 shorts
    unsigned short* w2bM  = w2aM + 8388608;
    unsigned short* e2nwM = w2bM + 8388608;                              // 524288 shorts

    k_front<<<dim3(2688), 256, 0, stream>>>(
        x, w2a, w2aM, w2b, w2bM, e2nw, e2nwM,
        w1a, b1a, w1b, b1b, A1, B1, adjw, rdegw, nodes_raw);
    k_e2e<<<dim3(512), 512, 0, stream>>>(A1, B1, w2aM, w2bM, part);
    k_red<<<dim3(64, 16), 256, 0, stream>>>(part, b2a, b2b, A2, B2);
    k_e2n<<<dim3(16, 8, 8), 256, 0, stream>>>(A2, B2, e2nwM, nodes_raw);
    k_tail<<<dim3(8), 256, 0, stream>>>(adjw, rdegw, nodes_raw, (const float*)d_in[10],
        (const float*)d_in[11], (const float*)d_in[12], (const float*)d_in[13], (const float*)d_in[14],
        (const float*)d_in[15], (const float*)d_in[16], (const float*)d_in[17], (const float*)d_in[18],
        (const float*)d_in[19], (const float*)d_in[20], (const float*)d_in[21], (const float*)d_in[22],
        (const float*)d_in[23], (const float*)d_in[24], (const float*)d_in[25], (const float*)d_in[26],
        (float*)d_out);
}

// Round 12
// 422.042 us; speedup vs baseline: 1.0329x; 1.0118x over previous
//
#include <hip/hip_runtime.h>

typedef short s16x8 __attribute__((ext_vector_type(8)));
typedef float f32x4 __attribute__((ext_vector_type(4)));
typedef float f32x2 __attribute__((ext_vector_type(2)));

#define TID threadIdx.x

__device__ __forceinline__ float lrelu_f(float x) { return fmaxf(x, 0.33f * x); }

// lrelu(pv+q.x), lrelu(pv+q.y) -> packed bf16x2 using HW v_cvt_pk_bf16_f32
__device__ __forceinline__ unsigned lrelu_pack(float pv, f32x2 q) {
    f32x2 s = q + pv;
    f32x2 m = s * 0.33f;
    f32x2 r = __builtin_elementwise_max(s, m);
    unsigned u;
    asm("v_cvt_pk_bf16_f32 %0, %1, %2" : "=v"(u) : "v"(r.x), "v"(r.y));
    return u;
}
__device__ __forceinline__ unsigned pk_bf16(float a, float b) {
    unsigned u;
    asm("v_cvt_pk_bf16_f32 %0, %1, %2" : "=v"(u) : "v"(a), "v"(b));
    return u;
}
__device__ __forceinline__ unsigned short bf16_of(float a) {
    unsigned u;
    asm("v_cvt_pk_bf16_f32 %0, %1, %2" : "=v"(u) : "v"(a), "v"(a));
    return (unsigned short)u;
}
__device__ __forceinline__ float f32_of_bf16(unsigned short u) {
    return __uint_as_float((unsigned)u << 16);
}

union FragU { s16x8 v; uint4 q; unsigned w[4]; };

// Pin a 16B fragment's registers live at this program point (anti-sink).
#define PIN(x) asm volatile("" : "+v"((x).w[0]), "+v"((x).w[1]), "+v"((x).w[2]), "+v"((x).w[3]))

// ------------------------------------------------------------------
// Kernel F (fused front stage), 2688 blocks x 256 thr, role by bid:
//   [0,1536)    : f32->bf16 converts (w2a, w2b, e2n_w)
//   [1536,2560) : A1 (row-major x, coalesced; 2 r per block)
//   [2560,2624) : B1 tiled (x tile staged coalesced into padded LDS)
//   [2624,2688) : adjacency bitmasks + rdeg + nodes_raw zeroing
// ------------------------------------------------------------------
__global__ __launch_bounds__(256) void k_front(
    const float* __restrict__ x,
    const float* __restrict__ w2a, unsigned short* __restrict__ w2aM,
    const float* __restrict__ w2b, unsigned short* __restrict__ w2bM,
    const float* __restrict__ e2nw, unsigned short* __restrict__ e2nwM,
    const float* __restrict__ w1a, const float* __restrict__ b1a,
    const float* __restrict__ w1b, const float* __restrict__ b1b,
    float* __restrict__ A1, float* __restrict__ B1,
    unsigned long long* __restrict__ adjw, float* __restrict__ rdegw,
    float* __restrict__ nodes_raw)
{
    const int bid = blockIdx.x;
    const int tid = TID;

    __shared__ float xr[2][256];     // l1a
    __shared__ float xs[64][36];     // l1b (padded)

    if (bid < 1536) {
        const int which = bid >> 9;
        const int inner = bid & 511;
        const float* s; unsigned short* d; int n4;
        if (which == 0)      { s = w2a;  d = w2aM;  n4 = 2097152; }
        else if (which == 1) { s = w2b;  d = w2bM;  n4 = 2097152; }
        else                 { s = e2nw; d = e2nwM; n4 = 131072; }
        for (int i = inner * 256 + tid; i < n4; i += 131072) {
            float4 v = ((const float4*)s)[i];
            ((uint2*)d)[i] = make_uint2(pk_bf16(v.x, v.y), pk_bf16(v.z, v.w));
        }
    } else if (bid < 2560) {
        const int idx = bid - 1536;
        const int rp = idx & 127, b = idx >> 7;
        const int h = tid >> 7, ctid = tid & 127;
        const int r = rp * 2 + h;
        const float* xb = x + b * 65536;
        xr[h][ctid]       = xb[r * 256 + ctid];
        xr[h][ctid + 128] = xb[r * 256 + ctid + 128];
        __syncthreads();
        float acc = b1a[ctid];
        const float* wr = w1a + ctid * 256;
        #pragma unroll 4
        for (int q = 0; q < 256; q += 8) {
            float4 a = *(const float4*)(wr + q);
            float4 c = *(const float4*)(wr + q + 4);
            acc += xr[h][q + 0] * a.x + xr[h][q + 1] * a.y + xr[h][q + 2] * a.z + xr[h][q + 3] * a.w;
            acc += xr[h][q + 4] * c.x + xr[h][q + 5] * c.y + xr[h][q + 6] * c.z + xr[h][q + 7] * c.w;
        }
        A1[b * 32768 + ctid * 256 + r] = acc;
    } else if (bid < 2624) {
        const int idx = bid - 2560;
        const int jt = idx & 7, b = idx >> 3;
        const int c = tid & 127, jh = tid >> 7;
        const float* xb = x + b * 65536;
        float acc[16];
        #pragma unroll
        for (int jj = 0; jj < 16; ++jj) acc[jj] = 0.0f;
        for (int ch = 0; ch < 4; ++ch) {
            const int i0 = ch * 64;
            {
                const int row = tid >> 2, seg = tid & 3;
                const float* src = xb + (i0 + row) * 256 + jt * 32 + seg * 8;
                float4 a0 = *(const float4*)src;
                float4 a1 = *(const float4*)(src + 4);
                *(float4*)&xs[row][seg * 8]     = a0;
                *(float4*)&xs[row][seg * 8 + 4] = a1;
            }
            __syncthreads();
            const float* wrow = w1b + c * 256 + i0;
            #pragma unroll
            for (int i4 = 0; i4 < 64; i4 += 4) {
                float4 wv = *(const float4*)(wrow + i4);
                #pragma unroll
                for (int u = 0; u < 4; ++u) {
                    const float wsc = (u == 0) ? wv.x : (u == 1) ? wv.y : (u == 2) ? wv.z : wv.w;
                    const float* xrow = &xs[i4 + u][jh * 16];
                    #pragma unroll
                    for (int jj = 0; jj < 16; ++jj)
                        acc[jj] += wsc * xrow[jj];
                }
            }
            __syncthreads();
        }
        const float bias = b1b[c];
        float* outp = B1 + b * 32768 + c * 256 + jt * 32 + jh * 16;
        #pragma unroll
        for (int jj = 0; jj < 16; ++jj) outp[jj] = acc[jj] + bias;
    } else {
        const int idx = bid - 2624;
        nodes_raw[idx * 256 + tid] = 0.0f;
        const int gx = idx & 7, b = idx >> 3;
        const int wv = tid >> 6, lane = tid & 63;
        const int rbase = gx * 32 + wv * 8;
        for (int rr = 0; rr < 8; ++rr) {
            const int row = rbase + rr;
            int d = 0;
            unsigned long long w[4];
            #pragma unroll
            for (int k = 0; k < 4; ++k) {
                float v = x[b * 65536 + row * 256 + k * 64 + lane];
                w[k] = __ballot(v > 0.0f);
                d += __popcll(w[k]);
            }
            if (lane == 0) {
                #pragma unroll
                for (int k = 0; k < 4; ++k) adjw[(b * 256 + row) * 4 + k] = w[k];
                rdegw[b * 256 + row] = d ? 1.0f / (float)d : 0.0f;
            }
        }
    }
}

// ------------------------------------------------------------------
// Kernel 2: partial[s,bw,p,r] = sum_{c in slice16, q} lrelu(P[c,r]+Q[c,q]) * W[p,c,q]
// ROUND-11 STRUCTURE (passed, 135 us, best) with ONE change: part is
// stored as BF16 (halves the 33.5 MB part write + k_red's re-read;
// partials are O(1), bf16 error ~0.004/elem, 8x under the abs threshold).
// Per-quad store pattern stays 32B-contiguous (16 lanes x 2B).
// ------------------------------------------------------------------
__global__ __launch_bounds__(512, 4) void k_e2e(
    const float* __restrict__ A1, const float* __restrict__ B1,
    const unsigned short* __restrict__ w2aM, const unsigned short* __restrict__ w2bM,
    unsigned short* __restrict__ part)
{
    const int bid = blockIdx.x;
    const int xcd = bid & 7, tt = bid >> 3;       // 512 blocks
    const int hi = tt >> 5, inner = tt & 31;      // hi 0..1
    const int slice = xcd + 8 * hi;               // 0..15 = (s,which)
    const int s = slice >> 1, which = slice & 1;
    const int rt = inner >> 3, b = inner & 7;     // rt 0..3, b 0..7
    const int bw = b * 2 + which;

    const float* P = (which ? B1 : A1) + b * 32768;
    const float* Q = (which ? A1 : B1) + b * 32768;
    const unsigned short* W = which ? w2bM : w2aM;
    const int c0 = s * 16, r0 = rt * 64;

    __shared__ float Qs[16][256];   // 16 KB
    __shared__ float Ps[16][64];    // 4 KB
    __shared__ uint4 Hs[2048];      // 32 KB

    const int tid = TID;
    const int wave = tid >> 6, lane = tid & 63, quad = lane >> 4, l16 = lane & 15;
    const int pbase = wave * 32;

    {
        const float4* Qg = (const float4*)(Q + c0 * 256);
        float4* Qd = (float4*)&Qs[0][0];
        Qd[tid]       = Qg[tid];
        Qd[tid + 512] = Qg[tid + 512];
        int row = tid >> 5, c2 = (tid & 31) * 2;
        *(float2*)&Ps[row][c2] = *(const float2*)&P[(c0 + row) * 256 + r0 + c2];
    }
    __syncthreads();

    // ---- produce H(c=0): wave w owns q-chunk qc=w ----
    {
        const int qb = wave * 32 + quad * 8;
        f32x2 qp0 = *(const f32x2*)&Qs[0][qb + 0];
        f32x2 qp1 = *(const f32x2*)&Qs[0][qb + 2];
        f32x2 qp2 = *(const f32x2*)&Qs[0][qb + 4];
        f32x2 qp3 = *(const f32x2*)&Qs[0][qb + 6];
        #pragma unroll
        for (int rf = 0; rf < 4; ++rf) {
            float pv = Ps[0][rf * 16 + l16];
            uint4 u;
            u.x = lrelu_pack(pv, qp0);
            u.y = lrelu_pack(pv, qp1);
            u.z = lrelu_pack(pv, qp2);
            u.w = lrelu_pack(pv, qp3);
            Hs[(wave * 4 + rf) * 64 + lane] = u;
        }
    }

    f32x4 acc[2][4] = {};
    const unsigned short* Wrow[2];
    #pragma unroll
    for (int pf = 0; pf < 2; ++pf)
        Wrow[pf] = W + (size_t)(pbase + pf * 16 + l16) * 32768 + c0 * 256 + quad * 8;

    FragU af[2][2];
    #pragma unroll
    for (int pf = 0; pf < 2; ++pf) af[0][pf].q = *(const uint4*)(Wrow[pf]);

    __syncthreads();   // Hs(0) ready

    for (int c = 0; c < 16; ++c) {
        FragU hbf[2][4];
        #pragma unroll
        for (int nf = 0; nf < 4; ++nf)
            hbf[0][nf].q = Hs[nf * 64 + lane];

        #pragma unroll
        for (int q0 = 0; q0 < 8; ++q0) {
            const int cur = q0 & 1, nxt = cur ^ 1;
            // W prefetch for next step (crosses channel boundary freely)
            const int cn = c + ((q0 + 1) >> 3), qn = (q0 + 1) & 7;
            if (cn < 16) {
                #pragma unroll
                for (int pf = 0; pf < 2; ++pf)
                    af[nxt][pf].q = *(const uint4*)(Wrow[pf] + cn * 256 + qn * 32);
            }
            // H frag prefetch for next qc (same channel only)
            if (q0 < 7) {
                #pragma unroll
                for (int nf = 0; nf < 4; ++nf)
                    hbf[nxt][nf].q = Hs[((q0 + 1) * 4 + nf) * 64 + lane];
            }
            // 8 MFMAs
            #pragma unroll
            for (int nf = 0; nf < 4; ++nf)
                #pragma unroll
                for (int pf = 0; pf < 2; ++pf)
                    acc[pf][nf] = __builtin_amdgcn_mfma_f32_16x16x32_bf16(af[cur][pf].v, hbf[cur][nf].v, acc[pf][nf], 0, 0, 0);
            // Pin prefetched fragments live after the MFMA shadow.
            if (cn < 16) { PIN(af[nxt][0]); PIN(af[nxt][1]); }
            if (q0 < 7)  { PIN(hbf[nxt][0]); PIN(hbf[nxt][1]); PIN(hbf[nxt][2]); PIN(hbf[nxt][3]); }
        }
        __syncthreads();   // done reading Hs(c)
        if (c + 1 < 16) {
            const int qb = wave * 32 + quad * 8;
            f32x2 qp0 = *(const f32x2*)&Qs[c + 1][qb + 0];
            f32x2 qp1 = *(const f32x2*)&Qs[c + 1][qb + 2];
            f32x2 qp2 = *(const f32x2*)&Qs[c + 1][qb + 4];
            f32x2 qp3 = *(const f32x2*)&Qs[c + 1][qb + 6];
            #pragma unroll
            for (int rf = 0; rf < 4; ++rf) {
                float pv = Ps[c + 1][rf * 16 + l16];
                uint4 u;
                u.x = lrelu_pack(pv, qp0);
                u.y = lrelu_pack(pv, qp1);
                u.z = lrelu_pack(pv, qp2);
                u.w = lrelu_pack(pv, qp3);
                Hs[(wave * 4 + rf) * 64 + lane] = u;
            }
            __syncthreads();   // Hs(c+1) ready
        }
    }

    unsigned short* pb = part + (size_t)(s * 16 + bw) * 65536;
    #pragma unroll
    for (int pf = 0; pf < 2; ++pf)
        #pragma unroll
        for (int nf = 0; nf < 4; ++nf)
            #pragma unroll
            for (int t = 0; t < 4; ++t) {
                int p = pbase + pf * 16 + quad * 4 + t;
                int r = r0 + nf * 16 + l16;
                pb[p * 256 + r] = bf16_of(acc[pf][nf][t]);
            }
}

// ------------------------------------------------------------------
// Kernel 2b: A2/B2 = sum_s bf16-part + bias. grid (64, 16), block 256.
// Reads 4 bf16 (uint2) per s-slice per thread; f32 accumulate; f32 out.
// ------------------------------------------------------------------
__global__ __launch_bounds__(256) void k_red(
    const unsigned short* __restrict__ part,
    const float* __restrict__ b2a, const float* __restrict__ b2b,
    float* __restrict__ A2, float* __restrict__ B2)
{
    const int bw = blockIdx.y; const int b = bw >> 1, which = bw & 1;
    const int idx = blockIdx.x * 256 + TID;
    const uint2* pp = (const uint2*)part;   // 4 bf16 per uint2
    float4 acc = make_float4(0.f, 0.f, 0.f, 0.f);
    #pragma unroll
    for (int s = 0; s < 8; ++s) {
        uint2 v = pp[(size_t)(s * 16 + bw) * 16384 + idx];
        acc.x += f32_of_bf16((unsigned short)(v.x & 0xffff));
        acc.y += f32_of_bf16((unsigned short)(v.x >> 16));
        acc.z += f32_of_bf16((unsigned short)(v.y & 0xffff));
        acc.w += f32_of_bf16((unsigned short)(v.y >> 16));
    }
    const int p = idx >> 6;
    const float bias = (which ? b2b : b2a)[p];
    acc.x += bias; acc.y += bias; acc.z += bias; acc.w += bias;
    float* OUT = (which ? B2 : A2) + b * 65536;
    ((float4*)OUT)[idx] = acc;
}

// ------------------------------------------------------------------
// Kernel 3: nodes_raw[b,i,p] += sum_{c slice,q} lrelu(A2[c,i]+B2[c,q])*e2n_w[p,c,q]
// grid (16 it, 8 b, 8 sn), block 256 (4 waves c-split), prefetched, atomic out.
// ------------------------------------------------------------------
__global__ __launch_bounds__(256) void k_e2n(
    const float* __restrict__ A2, const float* __restrict__ B2,
    const unsigned short* __restrict__ e2nw,
    float* __restrict__ nodes_raw)
{
    const int it = blockIdx.x, b = blockIdx.y, sn = blockIdx.z;
    const int tid = TID, wave = tid >> 6, lane = tid & 63, quad = lane >> 4, l16 = lane & 15;
    const int i0 = it * 16;
    const int c0 = sn * 32 + wave * 8;
    const float* Ab = A2 + b * 65536;
    const float* Bb = B2 + b * 65536;
    const float* Brow0 = Bb + c0 * 256 + quad * 8;
    const unsigned short* Wrow0 = e2nw + (size_t)l16 * 65536 + c0 * 256 + quad * 8;

    f32x4 acc = {};
    FragU af[2];
    f32x2 qp[2][4];
    float pv, pvn;

    if (l16 < 8) af[0].q = *(const uint4*)(Wrow0);
    else         af[0].q = make_uint4(0u, 0u, 0u, 0u);
    #pragma unroll
    for (int k = 0; k < 4; ++k) qp[0][k] = *(const f32x2*)(Brow0 + 2 * k);
    pv = Ab[c0 * 256 + i0 + l16];

    for (int cc = 0; cc < 8; ++cc) {
        #pragma unroll
        for (int q0 = 0; q0 < 8; ++q0) {
            const int cur = q0 & 1, nxt = cur ^ 1;
            const int cn = (q0 == 7) ? cc + 1 : cc;
            const int qn = (q0 + 1) & 7;
            if (cn < 8) {
                if (l16 < 8) af[nxt].q = *(const uint4*)(Wrow0 + cn * 256 + qn * 32);
                else         af[nxt].q = make_uint4(0u, 0u, 0u, 0u);
                #pragma unroll
                for (int k = 0; k < 4; ++k)
                    qp[nxt][k] = *(const f32x2*)(Brow0 + cn * 256 + qn * 32 + 2 * k);
            }
            if (q0 == 4 && cc + 1 < 8) pvn = Ab[(c0 + cc + 1) * 256 + i0 + l16];
            FragU hb;
            hb.w[0] = lrelu_pack(pv, qp[cur][0]);
            hb.w[1] = lrelu_pack(pv, qp[cur][1]);
            hb.w[2] = lrelu_pack(pv, qp[cur][2]);
            hb.w[3] = lrelu_pack(pv, qp[cur][3]);
            acc = __builtin_amdgcn_mfma_f32_16x16x32_bf16(af[cur].v, hb.v, acc, 0, 0, 0);
            if (q0 == 7) pv = pvn;
        }
    }
    __shared__ float red[4][16][16];
    #pragma unroll
    for (int t = 0; t < 4; ++t) red[wave][quad * 4 + t][l16] = acc[t];
    __syncthreads();
    const int row = tid >> 4, col = tid & 15;
    if (row < 8) {
        float ssum = red[0][row][col] + red[1][row][col] + red[2][row][col] + red[3][row][col];
        atomicAdd(&nodes_raw[b * 2048 + (i0 + col) * 8 + row], ssum);
    }
}

// ------------------------------------------------------------------
// Kernel 4: graph/pool/readout/MLP. One block per batch. f32 weights/out.
// ------------------------------------------------------------------
__global__ __launch_bounds__(256) void k_tail(
    const unsigned long long* __restrict__ adjw, const float* __restrict__ rdegw,
    const float* __restrict__ nodes_raw, const float* __restrict__ e2n_b,
    const float* __restrict__ a11_w, const float* __restrict__ a11_b,
    const float* __restrict__ a12_w, const float* __restrict__ a12_b,
    const float* __restrict__ g1_w,  const float* __restrict__ g1_b,
    const float* __restrict__ a21_w, const float* __restrict__ a21_b,
    const float* __restrict__ a22_w, const float* __restrict__ a22_b,
    const float* __restrict__ d1_w,  const float* __restrict__ d1_b,
    const float* __restrict__ d2_w,  const float* __restrict__ d2_b,
    const float* __restrict__ d3_w,  const float* __restrict__ d3_b,
    float* __restrict__ out)
{
    const int b = blockIdx.x;
    const int tid = TID;

    __shared__ unsigned long long adj[256][4];
    __shared__ float nod[256][8];
    __shared__ float rdeg[256];
    __shared__ float md[256];
    __shared__ float w1s[256];
    __shared__ float w2s[256];
    __shared__ int   selflag[256];
    __shared__ int   selidx[128];
    __shared__ float s1v[128];
    __shared__ float out1[128][8];
    __shared__ float aggL[128][8];
    __shared__ float h2L[128][8];
    __shared__ unsigned long long adj1[128][2];
    __shared__ float rdeg1[128];
    __shared__ float tA[128];
    __shared__ float w1t[128];
    __shared__ float w2t[128];
    __shared__ int   sel2flag[128];
    __shared__ int   sel2idx[64];
    __shared__ float s2v[64];
    __shared__ float out2[64][8];
    __shared__ float r1[16], r2[16], zz[16];
    __shared__ float z1[128];
    __shared__ float z2[64];

    if (tid < 128) { selidx[tid] = 0; s1v[tid] = 0.0f; }
    if (tid < 64)  { sel2idx[tid] = 0; s2v[tid] = 0.0f; }

    {
        #pragma unroll
        for (int k = 0; k < 4; ++k) adj[tid][k] = adjw[(b * 256 + tid) * 4 + k];
        rdeg[tid] = rdegw[b * 256 + tid];
        for (int f = 0; f < 8; ++f)
            nod[tid][f] = lrelu_f(nodes_raw[b * 2048 + tid * 8 + f] + e2n_b[f]);
    }
    __syncthreads();
    {
        float s = 0.0f;
        for (int f = 0; f < 8; ++f) s += nod[tid][f] * a11_w[f];
        md[tid] = s * rdeg[tid];
    }
    __syncthreads();
    {
        float s = 0.0f;
        for (int k = 0; k < 4; ++k) {
            unsigned long long m = adj[tid][k];
            while (m) { int j = __builtin_ctzll(m); m &= m - 1; s += md[k * 64 + j]; }
        }
        w1s[tid] = lrelu_f(s + a11_b[0]);
    }
    __syncthreads();
    md[tid] = w1s[tid] * a12_w[0] * rdeg[tid];
    __syncthreads();
    {
        float s = 0.0f;
        for (int k = 0; k < 4; ++k) {
            unsigned long long m = adj[tid][k];
            while (m) { int j = __builtin_ctzll(m); m &= m - 1; s += md[k * 64 + j]; }
        }
        w2s[tid] = 1.0f / (1.0f + expf(-(s + a12_b[0])));
    }
    __syncthreads();
    {
        const float my = w2s[tid];
        int cnt = 0;
        for (int j = 0; j < 256; ++j) {
            float o = w2s[j];
            cnt += (o > my) || (o == my && j < tid);
        }
        selflag[tid] = (cnt < 128) ? 1 : 0;
    }
    __syncthreads();
    if (selflag[tid]) {
        int pos = 0;
        for (int j = 0; j < tid; ++j) pos += selflag[j];
        if (pos < 128) { selidx[pos] = tid; s1v[pos] = w2s[tid]; }
    }
    __syncthreads();
    for (int k = tid; k < 1024; k += 256) {
        int t = k >> 3, f = k & 7;
        out1[t][f] = nod[selidx[t]][f] * (1.0f + s1v[t]);
    }
    __syncthreads();
    if (tid < 16) {
        int f = tid & 7;
        if (tid < 8) {
            float mx = -INFINITY;
            for (int t = 0; t < 128; ++t) mx = fmaxf(mx, out1[t][f]);
            r1[tid] = mx;
        } else {
            float s = 0.0f;
            for (int t = 0; t < 128; ++t) s += out1[t][f];
            r1[tid] = s * (1.0f / 128.0f);
        }
    }
    if (tid < 128) {
        unsigned long long wds[2] = {0ull, 0ull};
        const int gi = selidx[tid];
        for (int u = 0; u < 128; ++u) {
            const int gj = selidx[u];
            unsigned long long bit = (adj[gi][gj >> 6] >> (gj & 63)) & 1ull;
            wds[u >> 6] |= bit << (u & 63);
        }
        adj1[tid][0] = wds[0]; adj1[tid][1] = wds[1];
        int d = __popcll(wds[0]) + __popcll(wds[1]);
        rdeg1[tid] = d ? 1.0f / (float)d : 0.0f;
    }
    __syncthreads();
    {
        const int t = tid >> 1, f0 = (tid & 1) * 4;
        float a0 = 0, a1 = 0, a2 = 0, a3 = 0;
        for (int k = 0; k < 2; ++k) {
            unsigned long long m = adj1[t][k];
            while (m) {
                int u = __builtin_ctzll(m); m &= m - 1;
                int uu = k * 64 + u;
                float rr = rdeg1[uu];
                a0 += out1[uu][f0 + 0] * rr;
                a1 += out1[uu][f0 + 1] * rr;
                a2 += out1[uu][f0 + 2] * rr;
                a3 += out1[uu][f0 + 3] * rr;
            }
        }
        aggL[t][f0 + 0] = a0; aggL[t][f0 + 1] = a1; aggL[t][f0 + 2] = a2; aggL[t][f0 + 3] = a3;
    }
    __syncthreads();
    for (int k = tid; k < 1024; k += 256) {
        int t = k >> 3, fo = k & 7;
        float s = g1_b[fo];
        for (int f = 0; f < 8; ++f) s += aggL[t][f] * g1_w[fo * 8 + f];
        h2L[t][fo] = s;
    }
    __syncthreads();
    if (tid < 128) {
        float s = 0.0f;
        for (int f = 0; f < 8; ++f) s += h2L[tid][f] * a21_w[f];
        tA[tid] = s * rdeg1[tid];
    }
    __syncthreads();
    if (tid < 128) {
        float s = 0.0f;
        for (int k = 0; k < 2; ++k) {
            unsigned long long m = adj1[tid][k];
            while (m) { int u = __builtin_ctzll(m); m &= m - 1; s += tA[k * 64 + u]; }
        }
        w1t[tid] = lrelu_f(s + a21_b[0]);
    }
    __syncthreads();
    if (tid < 128) tA[tid] = w1t[tid] * a22_w[0] * rdeg1[tid];
    __syncthreads();
    if (tid < 128) {
        float s = 0.0f;
        for (int k = 0; k < 2; ++k) {
            unsigned long long m = adj1[tid][k];
            while (m) { int u = __builtin_ctzll(m); m &= m - 1; s += tA[k * 64 + u]; }
        }
        w2t[tid] = 1.0f / (1.0f + expf(-(s + a22_b[0])));
    }
    __syncthreads();
    if (tid < 128) {
        const float my = w2t[tid];
        int cnt = 0;
        for (int u = 0; u < 128; ++u) {
            float o = w2t[u];
            cnt += (o > my) || (o == my && u < tid);
        }
        sel2flag[tid] = (cnt < 64) ? 1 : 0;
    }
    __syncthreads();
    if (tid < 128 && sel2flag[tid]) {
        int pos = 0;
        for (int u = 0; u < tid; ++u) pos += sel2flag[u];
        if (pos < 64) { sel2idx[pos] = tid; s2v[pos] = w2t[tid]; }
    }
    __syncthreads();
    for (int k = tid; k < 512; k += 256) {
        int u = k >> 3, f = k & 7;
        out2[u][f] = h2L[sel2idx[u]][f] * (1.0f + s2v[u]);
    }
    __syncthreads();
    if (tid < 16) {
        int f = tid & 7;
        if (tid < 8) {
            float mx = -INFINITY;
            for (int t = 0; t < 64; ++t) mx = fmaxf(mx, out2[t][f]);
            r2[tid] = mx;
        } else {
            float s = 0.0f;
            for (int t = 0; t < 64; ++t) s += out2[t][f];
            r2[tid] = s * (1.0f / 64.0f);
        }
    }
    __syncthreads();
    if (tid < 16) zz[tid] = r1[tid] + r2[tid];
    __syncthreads();
    if (tid < 128) {
        float s = d1_b[tid];
        for (int k = 0; k < 16; ++k) s += zz[k] * d1_w[tid * 16 + k];
        z1[tid] = lrelu_f(s);
    }
    __syncthreads();
    if (tid < 64) {
        float s = d2_b[tid];
        for (int k = 0; k < 128; ++k) s += z1[k] * d2_w[tid * 128 + k];
        z2[tid] = lrelu_f(s);
    }
    __syncthreads();
    if (tid == 0) {
        float s = d3_b[0];
        for (int k = 0; k < 64; ++k) s += z2[k] * d3_w[k];
        out[b] = s;
    }
}

// ------------------------------------------------------------------
extern "C" void kernel_launch(void* const* d_in, const int* in_sizes, int n_in,
                              void* d_out, int out_size, void* d_ws, size_t ws_size,
                              hipStream_t stream) {
    const float* x     = (const float*)d_in[0];
    const float* w1a   = (const float*)d_in[1];
    const float* b1a   = (const float*)d_in[2];
    const float* w1b   = (const float*)d_in[3];
    const float* b1b   = (const float*)d_in[4];
    const float* w2a   = (const float*)d_in[5];
    const float* b2a   = (const float*)d_in[6];
    const float* w2b   = (const float*)d_in[7];
    const float* b2b   = (const float*)d_in[8];
    const float* e2nw  = (const float*)d_in[9];

    float* ws        = (float*)d_ws;
    float* A1        = ws;                     // 262144
    float* B1        = ws + 262144;            // 262144
    float* A2        = ws + 524288;            // 524288
    float* B2        = ws + 1048576;           // 524288
    float* nodes_raw = ws + 1572864;           // 16384
    float* rdegw     = ws + 1589248;           // 8192 (oversized, 2048 used)
    unsigned long long* adjw = (unsigned long long*)(ws + 1597440); // 8192 ull = 16384 f
    unsigned short* part = (unsigned short*)(ws + 1613824);          // 8388608 shorts (bf16)
    unsigned short* w2aM  = (unsigned short*)(ws + 10002432);            // 8388608 shorts
    unsigned short* w2bM  = w2aM + 8388608;
    unsigned short* e2nwM = w2bM + 8388608;                              // 524288 shorts

    k_front<<<dim3(2688), 256, 0, stream>>>(
        x, w2a, w2aM, w2b, w2bM, e2nw, e2nwM,
        w1a, b1a, w1b, b1b, A1, B1, adjw, rdegw, nodes_raw);
    k_e2e<<<dim3(512), 512, 0, stream>>>(A1, B1, w2aM, w2bM, part);
    k_red<<<dim3(64, 16), 256, 0, stream>>>(part, b2a, b2b, A2, B2);
    k_e2n<<<dim3(16, 8, 8), 256, 0, stream>>>(A2, B2, e2nwM, nodes_raw);
    k_tail<<<dim3(8), 256, 0, stream>>>(adjw, rdegw, nodes_raw, (const float*)d_in[10],
        (const float*)d_in[11], (const float*)d_in[12], (const float*)d_in[13], (const float*)d_in[14],
        (const float*)d_in[15], (const float*)d_in[16], (const float*)d_in[17], (const float*)d_in[18],
        (const float*)d_in[19], (const float*)d_in[20], (const float*)d_in[21], (const float*)d_in[22],
        (const float*)d_in[23], (const float*)d_in[24], (const float*)d_in[25], (const float*)d_in[26],
        (float*)d_out);
}